// Round 10
// baseline (110.353 us; speedup 1.0000x reference)
//
#include <hip/hip_runtime.h>
#include <hip/hip_fp16.h>

#define CELL 128
#define STEPS 20

typedef _Float16 half8_t __attribute__((ext_vector_type(8)));
typedef float    floatx4 __attribute__((ext_vector_type(4)));

__device__ __forceinline__ unsigned packf2(float x, float y) {
    typedef _Float16 h2 __attribute__((ext_vector_type(2)));
    h2 h = { (_Float16)x, (_Float16)y };
    return __builtin_bit_cast(unsigned, h);
}
__device__ __forceinline__ float h2lo(unsigned u) {
    typedef _Float16 h2 __attribute__((ext_vector_type(2)));
    h2 h = __builtin_bit_cast(h2, u); return (float)h[0];
}
__device__ __forceinline__ float h2hi(unsigned u) {
    typedef _Float16 h2 __attribute__((ext_vector_type(2)));
    h2 h = __builtin_bit_cast(h2, u); return (float)h[1];
}

__device__ __forceinline__ float fast_sigmoid(float x) { return 1.0f / (1.0f + __expf(-x)); }
__device__ __forceinline__ float fast_tanh(float x) {
    return 2.0f / (1.0f + __expf(-2.0f * x)) - 1.0f;
}

// One 512-thread workgroup (8 waves) runs the whole 20-step recurrence.
//
// REGISTER MODEL (R4-R9): per-wave budget = 2048 VGPR/CU / resident waves;
// launch_bounds 2nd arg = min BLOCKS/CU. 16 waves -> 128 total (R9 spilled:
// 64 arch + AGPR + 16 scratch). (512,1) => 8 waves => 256/thread — the 4-tile
// weight set (~176 live dwords) fits with slack. Full unroll everywhere
// (R6: partial unroll demotes local arrays to scratch).
//
// PIPELINE (2 barriers/step): window A = MFMA gate matvec (4 16-col B-tiles/
// wave, K=256, 8 broadcast ds_read_b128) + head-logits(t-1) on waves 0..5
// (h(t-1) read as packed f16 from xh2) + softmax(t-2) (double-buffered
// logits, parity (t-1)&1 vs (t-2)&1). window B = LSTM elementwise on threads
// 0..127 (c in regs, h packed to xh2 via shfl_xor) + wave 2 copies x(t+1).
extern "C" __global__ void __launch_bounds__(512, 1)
nas_policy_kernel(const int* __restrict__ net,
                  const float* __restrict__ emb_start,   // [1][128]
                  const float* __restrict__ emb_keys,    // [4][6][128]
                  const float* __restrict__ fc_W,        // [4][6][128]
                  const float* __restrict__ fc_b,        // [4][6]
                  const float* __restrict__ W_ih,        // [512][128]
                  const float* __restrict__ W_hh,        // [512][128]
                  const float* __restrict__ b_ih,        // [512]
                  const float* __restrict__ b_hh,        // [512]
                  float* __restrict__ out)               // [20][1][6] fp32
{
    const int t0   = threadIdx.x;    // 0..511
    const int wv   = t0 >> 6;        // wave 0..7
    const int lane = t0 & 63;
    const int quad = lane >> 4;      // 0..3
    const int lcol = lane & 15;

    __shared__ __align__(16) unsigned xh2[2 * 64];      // packed half2: [0..63]=x, [64..127]=h
    __shared__ __align__(16) unsigned s_embk2[24 * 64]; // emb_keys packed half2
    __shared__ float gates[4 * CELL];
    __shared__ float s_fcW[24 * CELL];                  // fc head fp32
    __shared__ float s_fcb[24];
    __shared__ float logits[2 * 8];                     // double-buffered by step parity
    __shared__ int   s_net[STEPS];

    // ---- B-fragments: wave wv owns gate rows wv*64 .. wv*64+63 as four
    //      16-col tiles; bfi[kc][j] = Wcat[r_i][32*kc + quad*8 + j] ----
    const int rbase = wv << 6;
    const int r0 = rbase + lcol, r1 = r0 + 16, r2 = r0 + 32, r3 = r0 + 48;
    half8_t bf0[8], bf1[8], bf2[8], bf3[8];
#pragma unroll
    for (int kc = 0; kc < 8; ++kc) {                    // FULL unroll
        const int k0 = (kc << 5) + (quad << 3);         // 0..255
        const float* base = (k0 < 128) ? W_ih + k0 : W_hh + (k0 - 128);
#define LD8(dst, row) { \
        const float4* p4 = (const float4*)(base + (row) * CELL); \
        float4 a = p4[0], b = p4[1]; \
        dst = half8_t{ (_Float16)a.x, (_Float16)a.y, (_Float16)a.z, (_Float16)a.w, \
                       (_Float16)b.x, (_Float16)b.y, (_Float16)b.z, (_Float16)b.w }; }
        LD8(bf0[kc], r0) LD8(bf1[kc], r1) LD8(bf2[kc], r2) LD8(bf3[kc], r3)
#undef LD8
    }
    const float bias0 = b_ih[r0] + b_hh[r0];
    const float bias1 = b_ih[r1] + b_hh[r1];
    const float bias2 = b_ih[r2] + b_hh[r2];
    const float bias3 = b_ih[r3] + b_hh[r3];

    // ---- stage small tensors; init x, h ----
    {
        const float2* ek2 = (const float2*)emb_keys;
        for (int i = t0; i < 24 * 64; i += 512) {
            float2 v = ek2[i];
            s_embk2[i] = packf2(v.x, v.y);
        }
        for (int i = t0; i < 24 * CELL; i += 512) s_fcW[i] = fc_W[i];
        if (t0 < 24)    s_fcb[t0] = fc_b[t0];
        if (t0 < STEPS) s_net[t0] = net[t0];
        if (t0 < 64) {
            float2 v = ((const float2*)emb_start)[t0];
            xh2[t0]      = packf2(v.x, v.y);            // x0 = emb_start
            xh2[64 + t0] = 0u;                          // h(-1) = 0
        }
    }
    float c = 0.0f;

    for (int t = 0; t < STEPS; ++t) {
        __syncthreads();   // A-barrier: xh2 = (x(t), h(t-1)) ready

        // ======== window A ========
        // MFMA gate matvec: A = x|h broadcast to all 16 rows (one 16-lane-
        // broadcast b128 per k-chunk), B = weight tiles in regs.
        floatx4 acc0 = {0,0,0,0}, acc1 = {0,0,0,0}, acc2 = {0,0,0,0}, acc3 = {0,0,0,0};
        const uint4* xp = (const uint4*)xh2;            // 32 uint4 = 256 f16
#pragma unroll
        for (int kc = 0; kc < 8; ++kc) {
            uint4 u = xp[(kc << 2) + quad];
            half8_t af = __builtin_bit_cast(half8_t, u);
            acc0 = __builtin_amdgcn_mfma_f32_16x16x32_f16(af, bf0[kc], acc0, 0, 0, 0);
            acc1 = __builtin_amdgcn_mfma_f32_16x16x32_f16(af, bf1[kc], acc1, 0, 0, 0);
            acc2 = __builtin_amdgcn_mfma_f32_16x16x32_f16(af, bf2[kc], acc2, 0, 0, 0);
            acc3 = __builtin_amdgcn_mfma_f32_16x16x32_f16(af, bf3[kc], acc3, 0, 0, 0);
        }
        if (lane < 16) {   // C rows identical (A broadcast): acc[0], col=lane
            gates[rbase + lane]      = acc0[0] + bias0;
            gates[rbase + 16 + lane] = acc1[0] + bias1;
            gates[rbase + 32 + lane] = acc2[0] + bias2;
            gates[rbase + 48 + lane] = acc3[0] + bias3;
        }

        // head logits of step t-1 (waves 0..5), h(t-1) as packed f16 from xh2
        if (t >= 1 && wv < 6) {
            const int ti = t - 1;
            unsigned hu = xh2[64 + lane];
            const float* Wr = s_fcW + (((ti & 3) * 6) + wv) * CELL;
            float p2 = h2lo(hu) * Wr[2 * lane] + h2hi(hu) * Wr[2 * lane + 1];
#pragma unroll
            for (int off = 32; off >= 1; off >>= 1) p2 += __shfl_down(p2, off);
            if (lane == 0)
                logits[((ti & 1) << 3) + wv] = p2 + s_fcb[(ti & 3) * 6 + wv];
        }

        // softmax of step t-2 (threads 0..5); buffer parity (t-2)&1 == t&1
        if (t >= 2 && t0 < 6) {
            const float* L = logits + ((t & 1) << 3);
            float l0 = L[0], l1 = L[1], l2 = L[2], l3 = L[3], l4 = L[4], l5 = L[5];
            float m = fmaxf(fmaxf(fmaxf(l0, l1), fmaxf(l2, l3)), fmaxf(l4, l5));
            float e0 = __expf(l0 - m), e1 = __expf(l1 - m), e2 = __expf(l2 - m);
            float e3 = __expf(l3 - m), e4 = __expf(l4 - m), e5 = __expf(l5 - m);
            float s = ((e0 + e1) + (e2 + e3)) + (e4 + e5);
            float mine = (t0 == 0) ? e0 : (t0 == 1) ? e1 : (t0 == 2) ? e2
                       : (t0 == 3) ? e3 : (t0 == 4) ? e4 : e5;
            out[(t - 2) * 6 + t0] = mine / s;
        }

        __syncthreads();   // B-barrier: gates ready; head reads of h(t-1) done

        // ======== window B ========
        if (t0 < CELL) {   // LSTM elementwise; c persists in regs (waves 0,1)
            float ig = fast_sigmoid(gates[t0]);
            float fg = fast_sigmoid(gates[CELL + t0]);
            float gg = fast_tanh   (gates[2 * CELL + t0]);
            float og = fast_sigmoid(gates[3 * CELL + t0]);
            c = fg * c + ig * gg;
            float h = og * fast_tanh(c);
            float hp = __shfl_xor(h, 1);                // partner cell's h
            if ((t0 & 1) == 0)
                xh2[64 + (t0 >> 1)] = packf2(h, hp);    // pack h(t)
        } else if (wv == 2 && t < STEPS - 1) {
            // x(t+1) = emb_keys[(t+1)%4][net[t+1]] (packed copy)
            xh2[lane] = s_embk2[((((t + 1) & 3) * 6) + s_net[t + 1]) * 64 + lane];
        }
    }

    // ======== epilogue ========
    __syncthreads();       // h(19) packed; logits(18) in buffer parity 0
    if (wv < 6) {          // head logits of step 19 -> parity 1
        unsigned hu = xh2[64 + lane];
        const float* Wr = s_fcW + (((19 & 3) * 6) + wv) * CELL;
        float p2 = h2lo(hu) * Wr[2 * lane] + h2hi(hu) * Wr[2 * lane + 1];
#pragma unroll
        for (int off = 32; off >= 1; off >>= 1) p2 += __shfl_down(p2, off);
        if (lane == 0) logits[((19 & 1) << 3) + wv] = p2 + s_fcb[(19 & 3) * 6 + wv];
    }
    if (t0 < 6) {          // softmax(18), parity 0
        const float* L = logits + ((18 & 1) << 3);
        float l0 = L[0], l1 = L[1], l2 = L[2], l3 = L[3], l4 = L[4], l5 = L[5];
        float m = fmaxf(fmaxf(fmaxf(l0, l1), fmaxf(l2, l3)), fmaxf(l4, l5));
        float e0 = __expf(l0 - m), e1 = __expf(l1 - m), e2 = __expf(l2 - m);
        float e3 = __expf(l3 - m), e4 = __expf(l4 - m), e5 = __expf(l5 - m);
        float s = ((e0 + e1) + (e2 + e3)) + (e4 + e5);
        float mine = (t0 == 0) ? e0 : (t0 == 1) ? e1 : (t0 == 2) ? e2
                   : (t0 == 3) ? e3 : (t0 == 4) ? e4 : e5;
        out[18 * 6 + t0] = mine / s;
    }
    __syncthreads();
    if (t0 < 6) {          // softmax(19), parity 1
        const float* L = logits + ((19 & 1) << 3);
        float l0 = L[0], l1 = L[1], l2 = L[2], l3 = L[3], l4 = L[4], l5 = L[5];
        float m = fmaxf(fmaxf(fmaxf(l0, l1), fmaxf(l2, l3)), fmaxf(l4, l5));
        float e0 = __expf(l0 - m), e1 = __expf(l1 - m), e2 = __expf(l2 - m);
        float e3 = __expf(l3 - m), e4 = __expf(l4 - m), e5 = __expf(l5 - m);
        float s = ((e0 + e1) + (e2 + e3)) + (e4 + e5);
        float mine = (t0 == 0) ? e0 : (t0 == 1) ? e1 : (t0 == 2) ? e2
                   : (t0 == 3) ? e3 : (t0 == 4) ? e4 : e5;
        out[19 * 6 + t0] = mine / s;
    }
}

extern "C" void kernel_launch(void* const* d_in, const int* in_sizes, int n_in,
                              void* d_out, int out_size, void* d_ws, size_t ws_size,
                              hipStream_t stream) {
    (void)in_sizes; (void)n_in; (void)out_size; (void)d_ws; (void)ws_size;
    const int*   net       = (const int*)d_in[0];
    // d_in[1] = reward, unused in forward
    const float* emb_start = (const float*)d_in[2];
    const float* emb_keys  = (const float*)d_in[3];
    const float* fc_W      = (const float*)d_in[4];
    const float* fc_b      = (const float*)d_in[5];
    const float* W_ih      = (const float*)d_in[6];
    const float* W_hh      = (const float*)d_in[7];
    const float* b_ih      = (const float*)d_in[8];
    const float* b_hh      = (const float*)d_in[9];
    float*       out       = (float*)d_out;

    hipLaunchKernelGGL(nas_policy_kernel, dim3(1), dim3(512), 0, stream,
                       net, emb_start, emb_keys, fc_W, fc_b,
                       W_ih, W_hh, b_ih, b_hh, out);
}

// Round 11
// 103.784 us; speedup vs baseline: 1.0633x; 1.0633x over previous
//
#include <hip/hip_runtime.h>
#include <hip/hip_fp16.h>

#define CELL 128
#define STEPS 20

typedef _Float16 half8_t __attribute__((ext_vector_type(8)));
typedef float    floatx4 __attribute__((ext_vector_type(4)));

__device__ __forceinline__ unsigned packf2(float x, float y) {
    typedef _Float16 h2 __attribute__((ext_vector_type(2)));
    h2 h = { (_Float16)x, (_Float16)y };
    return __builtin_bit_cast(unsigned, h);
}
__device__ __forceinline__ float fdot2u(unsigned a, unsigned b, float c) {
    typedef _Float16 h2 __attribute__((ext_vector_type(2)));
#if __has_builtin(__builtin_amdgcn_fdot2)
    return __builtin_amdgcn_fdot2(__builtin_bit_cast(h2, a), __builtin_bit_cast(h2, b), c, false);
#else
    h2 x = __builtin_bit_cast(h2, a), y = __builtin_bit_cast(h2, b);
    return fmaf((float)x[0], (float)y[0], fmaf((float)x[1], (float)y[1], c));
#endif
}
__device__ __forceinline__ float fast_sigmoid(float x) { return 1.0f / (1.0f + __expf(-x)); }
__device__ __forceinline__ float fast_tanh(float x) {
    return 2.0f / (1.0f + __expf(-2.0f * x)) - 1.0f;
}

// ===== fragment spec (single source of truth, shared by converter & main) =====
// thread t0 in [0,512): wv=t0>>6, lane=t0&63, quad=lane>>4, lcol=lane&15
// tile tau in [0,4):  row r = (wv<<6) + (tau<<4) + lcol
// chunk kc in [0,8):  k0  = (kc<<5) + (quad<<3); k<128 -> W_ih[r][k], else W_hh[r][k-128]
// frag u4 index F = t0*32 + kc*4 + tau ; ws layout: [0,256KB) frags, [256KB,+2KB) bias f32[512]

__global__ void __launch_bounds__(256)
nas_conv_kernel(const float* __restrict__ W_ih, const float* __restrict__ W_hh,
                const float* __restrict__ b_ih, const float* __restrict__ b_hh,
                uint4* __restrict__ wsf, float* __restrict__ wsb)
{
    const int tid = blockIdx.x * 256 + threadIdx.x;      // 0..8191 (32 blocks)
    for (int f = tid; f < 16384; f += 8192) {
        const int t0 = f >> 5, rem = f & 31, kc = rem >> 2, tau = rem & 3;
        const int wv = t0 >> 6, lane = t0 & 63, quad = lane >> 4, lcol = lane & 15;
        const int r  = (wv << 6) + (tau << 4) + lcol;
        const int k0 = (kc << 5) + (quad << 3);
        const float* src = (k0 < CELL) ? (W_ih + r * CELL + k0)
                                       : (W_hh + r * CELL + (k0 - CELL));
        float4 a = ((const float4*)src)[0], b = ((const float4*)src)[1];
        half8_t h = { (_Float16)a.x, (_Float16)a.y, (_Float16)a.z, (_Float16)a.w,
                      (_Float16)b.x, (_Float16)b.y, (_Float16)b.z, (_Float16)b.w };
        wsf[f] = __builtin_bit_cast(uint4, h);
    }
    if (tid < 512) wsb[tid] = b_ih[tid] + b_hh[tid];
}

// One 512-thread workgroup (8 waves) runs the 20-step recurrence.
// Window A (all waves): pure gate MFMA (4 16-col B-tiles, K=256, 8 broadcast
// ds_read_b128); wave 5 lanes 0-5 additionally do softmax(t-2) (logits
// double-buffered by parity). Window B: waves 0-1 LSTM elementwise (h packed
// to xh2 + parity-buffered hp2), wave 2 copies x(t+1), waves 2-7 compute the
// six head logits of step t-1 from hp2 parity (t-1)&1 (no race vs h(t) write).
extern "C" __global__ void __launch_bounds__(512, 1)
nas_policy_kernel(const int* __restrict__ net,
                  const float* __restrict__ emb_start,   // [1][128]
                  const float* __restrict__ emb_keys,    // [4][6][128]
                  const float* __restrict__ fc_W,        // [4][6][128]
                  const float* __restrict__ fc_b,        // [4][6]
                  const uint4* __restrict__ wsf,         // [16384] weight frags (f16)
                  const float* __restrict__ wsb,         // [512] fused bias
                  float* __restrict__ out)               // [20][1][6] fp32
{
    const int t0   = threadIdx.x;    // 0..511
    const int wv   = t0 >> 6;        // wave 0..7
    const int lane = t0 & 63;
    const int lcol = lane & 15;

    __shared__ __align__(16) unsigned xh2[2 * 64];      // half2: [0..63]=x(t), [64..127]=h(t-1)
    __shared__ __align__(16) unsigned hp2[2 * 64];      // h history, parity-buffered
    __shared__ __align__(16) unsigned s_embk2[24 * 64]; // emb_keys packed half2
    __shared__ unsigned s_fcw2[24 * 64];                // fc_W packed half2
    __shared__ float gates[4 * CELL];
    __shared__ float s_fcb[24];
    __shared__ float logits[2 * 8];                     // parity-buffered
    __shared__ int   s_net[STEPS];

    // ---- coalesced fragment load: 32 contiguous u4 per thread ----
    const uint4* wf = wsf + t0 * 32;
    half8_t bf0[8], bf1[8], bf2[8], bf3[8];
#pragma unroll
    for (int kc = 0; kc < 8; ++kc) {                    // FULL unroll (R6 lesson)
        bf0[kc] = __builtin_bit_cast(half8_t, wf[kc * 4 + 0]);
        bf1[kc] = __builtin_bit_cast(half8_t, wf[kc * 4 + 1]);
        bf2[kc] = __builtin_bit_cast(half8_t, wf[kc * 4 + 2]);
        bf3[kc] = __builtin_bit_cast(half8_t, wf[kc * 4 + 3]);
    }
    const int rb = (wv << 6) + lcol;
    const float bias0 = wsb[rb], bias1 = wsb[rb + 16], bias2 = wsb[rb + 32], bias3 = wsb[rb + 48];

    // ---- stage small tensors (f16 packs); init x, h ----
    {
        const float2* ek2 = (const float2*)emb_keys;
        const float2* fw2 = (const float2*)fc_W;
        for (int i = t0; i < 24 * 64; i += 512) {
            float2 v = ek2[i]; s_embk2[i] = packf2(v.x, v.y);
            float2 w = fw2[i]; s_fcw2[i]  = packf2(w.x, w.y);
        }
        if (t0 < 24)    s_fcb[t0] = fc_b[t0];
        if (t0 < STEPS) s_net[t0] = net[t0];
        if (t0 < 64) {
            float2 v = ((const float2*)emb_start)[t0];
            xh2[t0]      = packf2(v.x, v.y);            // x0 = emb_start
            xh2[64 + t0] = 0u;                          // h(-1) = 0
        }
    }
    float c = 0.0f;
    const int rbase = wv << 6;

    for (int t = 0; t < STEPS; ++t) {
        __syncthreads();   // A-barrier: xh2=(x(t),h(t-1)); logits(t-2) final

        // ======== window A ========
        floatx4 acc0 = {0,0,0,0}, acc1 = {0,0,0,0}, acc2 = {0,0,0,0}, acc3 = {0,0,0,0};
        const uint4* xp = (const uint4*)xh2;            // 32 u4 = 256 f16
        const int quad = lane >> 4;
#pragma unroll
        for (int kc = 0; kc < 8; ++kc) {
            uint4 u = xp[(kc << 2) + quad];             // 16-lane broadcast b128
            half8_t af = __builtin_bit_cast(half8_t, u);
            acc0 = __builtin_amdgcn_mfma_f32_16x16x32_f16(af, bf0[kc], acc0, 0, 0, 0);
            acc1 = __builtin_amdgcn_mfma_f32_16x16x32_f16(af, bf1[kc], acc1, 0, 0, 0);
            acc2 = __builtin_amdgcn_mfma_f32_16x16x32_f16(af, bf2[kc], acc2, 0, 0, 0);
            acc3 = __builtin_amdgcn_mfma_f32_16x16x32_f16(af, bf3[kc], acc3, 0, 0, 0);
        }
        if (lane < 16) {   // C rows identical (A broadcast): acc[0], col = lane
            gates[rbase + lane]      = acc0[0] + bias0;
            gates[rbase + 16 + lane] = acc1[0] + bias1;
            gates[rbase + 32 + lane] = acc2[0] + bias2;
            gates[rbase + 48 + lane] = acc3[0] + bias3;
        }

        // softmax(t-2) on wave 5 (logits parity (t-2)&1 == t&1; writers this
        // step use parity (t-1)&1 and only in window B -> no conflict)
        if (t >= 2 && wv == 5 && lane < 6) {
            const float* L = logits + ((t & 1) << 3);
            float l0 = L[0], l1 = L[1], l2 = L[2], l3 = L[3], l4 = L[4], l5 = L[5];
            float m = fmaxf(fmaxf(fmaxf(l0, l1), fmaxf(l2, l3)), fmaxf(l4, l5));
            float e0 = __expf(l0 - m), e1 = __expf(l1 - m), e2 = __expf(l2 - m);
            float e3 = __expf(l3 - m), e4 = __expf(l4 - m), e5 = __expf(l5 - m);
            float s = ((e0 + e1) + (e2 + e3)) + (e4 + e5);
            float mine = (lane == 0) ? e0 : (lane == 1) ? e1 : (lane == 2) ? e2
                       : (lane == 3) ? e3 : (lane == 4) ? e4 : e5;
            out[(t - 2) * 6 + lane] = mine / s;
        }

        __syncthreads();   // B-barrier: gates ready

        // ======== window B ========
        if (t0 < CELL) {   // LSTM elementwise (waves 0,1); c in regs
            float ig = fast_sigmoid(gates[t0]);
            float fg = fast_sigmoid(gates[CELL + t0]);
            float gg = fast_tanh   (gates[2 * CELL + t0]);
            float og = fast_sigmoid(gates[3 * CELL + t0]);
            c = fg * c + ig * gg;
            float h = og * fast_tanh(c);
            float hpv = __shfl_xor(h, 1);
            if ((t0 & 1) == 0) {
                unsigned u = packf2(h, hpv);
                xh2[64 + (t0 >> 1)] = u;                // h(t) for next gate MFMA
                hp2[((t & 1) << 6) + (t0 >> 1)] = u;    // h(t) parity copy for head
            }
        }
        if (wv == 2 && t < STEPS - 1) {                 // x(t+1)
            xh2[lane] = s_embk2[((((t + 1) & 3) * 6) + s_net[t + 1]) * 64 + lane];
        }
        if (t >= 1 && wv >= 2) {                        // head hd of step t-1
            const int ti = t - 1, hd = wv - 2;
            unsigned hu = hp2[((ti & 1) << 6) + lane];  // h(t-1), parity-safe
            unsigned wu = s_fcw2[(((ti & 3) * 6) + hd) * 64 + lane];
            float p = fdot2u(hu, wu, 0.0f);
#pragma unroll
            for (int off = 32; off >= 1; off >>= 1) p += __shfl_down(p, off);
            if (lane == 0)
                logits[((ti & 1) << 3) + hd] = p + s_fcb[(ti & 3) * 6 + hd];
        }
    }

    // ======== epilogue: head(19), softmax(18), softmax(19) ========
    __syncthreads();
    if (wv >= 2) {         // head(19): h(19) in hp2 parity 1 (written B(19))
        const int hd = wv - 2;
        unsigned hu = hp2[(1 << 6) + lane];
        unsigned wu = s_fcw2[(((19 & 3) * 6) + hd) * 64 + lane];
        float p = fdot2u(hu, wu, 0.0f);
#pragma unroll
        for (int off = 32; off >= 1; off >>= 1) p += __shfl_down(p, off);
        if (lane == 0) logits[(1 << 3) + hd] = p + s_fcb[(19 & 3) * 6 + hd];
    }
    if (wv == 0 && lane < 6) {   // softmax(18): parity 0, written in B(19)
        const float* L = logits + 0;
        float l0 = L[0], l1 = L[1], l2 = L[2], l3 = L[3], l4 = L[4], l5 = L[5];
        float m = fmaxf(fmaxf(fmaxf(l0, l1), fmaxf(l2, l3)), fmaxf(l4, l5));
        float e0 = __expf(l0 - m), e1 = __expf(l1 - m), e2 = __expf(l2 - m);
        float e3 = __expf(l3 - m), e4 = __expf(l4 - m), e5 = __expf(l5 - m);
        float s = ((e0 + e1) + (e2 + e3)) + (e4 + e5);
        float mine = (lane == 0) ? e0 : (lane == 1) ? e1 : (lane == 2) ? e2
                   : (lane == 3) ? e3 : (lane == 4) ? e4 : e5;
        out[18 * 6 + lane] = mine / s;
    }
    __syncthreads();
    if (wv == 0 && lane < 6) {   // softmax(19): parity 1
        const float* L = logits + 8;
        float l0 = L[0], l1 = L[1], l2 = L[2], l3 = L[3], l4 = L[4], l5 = L[5];
        float m = fmaxf(fmaxf(fmaxf(l0, l1), fmaxf(l2, l3)), fmaxf(l4, l5));
        float e0 = __expf(l0 - m), e1 = __expf(l1 - m), e2 = __expf(l2 - m);
        float e3 = __expf(l3 - m), e4 = __expf(l4 - m), e5 = __expf(l5 - m);
        float s = ((e0 + e1) + (e2 + e3)) + (e4 + e5);
        float mine = (lane == 0) ? e0 : (lane == 1) ? e1 : (lane == 2) ? e2
                   : (lane == 3) ? e3 : (lane == 4) ? e4 : e5;
        out[19 * 6 + lane] = mine / s;
    }
}

// ===== fallback: R10 kernel verbatim (used only if ws_size is too small) =====
extern "C" __global__ void __launch_bounds__(512, 1)
nas_policy_fb(const int* __restrict__ net, const float* __restrict__ emb_start,
              const float* __restrict__ emb_keys, const float* __restrict__ fc_W,
              const float* __restrict__ fc_b, const float* __restrict__ W_ih,
              const float* __restrict__ W_hh, const float* __restrict__ b_ih,
              const float* __restrict__ b_hh, float* __restrict__ out)
{
    const int t0 = threadIdx.x, wv = t0 >> 6, lane = t0 & 63;
    const int quad = lane >> 4, lcol = lane & 15;
    __shared__ __align__(16) unsigned xh2[2 * 64];
    __shared__ __align__(16) unsigned s_embk2[24 * 64];
    __shared__ float gates[4 * CELL];
    __shared__ float s_fcW[24 * CELL];
    __shared__ float s_fcb[24];
    __shared__ float logits[2 * 8];
    __shared__ int   s_net[STEPS];
    const int rbase = wv << 6;
    const int r0 = rbase + lcol, r1 = r0 + 16, r2 = r0 + 32, r3 = r0 + 48;
    half8_t bf0[8], bf1[8], bf2[8], bf3[8];
#pragma unroll
    for (int kc = 0; kc < 8; ++kc) {
        const int k0 = (kc << 5) + (quad << 3);
        const float* base = (k0 < 128) ? W_ih + k0 : W_hh + (k0 - 128);
#define LD8(dst, row) { const float4* p4 = (const float4*)(base + (row) * CELL); \
        float4 a = p4[0], b = p4[1]; \
        dst = half8_t{ (_Float16)a.x, (_Float16)a.y, (_Float16)a.z, (_Float16)a.w, \
                       (_Float16)b.x, (_Float16)b.y, (_Float16)b.z, (_Float16)b.w }; }
        LD8(bf0[kc], r0) LD8(bf1[kc], r1) LD8(bf2[kc], r2) LD8(bf3[kc], r3)
#undef LD8
    }
    const float bias0 = b_ih[r0] + b_hh[r0], bias1 = b_ih[r1] + b_hh[r1];
    const float bias2 = b_ih[r2] + b_hh[r2], bias3 = b_ih[r3] + b_hh[r3];
    {
        const float2* ek2 = (const float2*)emb_keys;
        for (int i = t0; i < 24 * 64; i += 512) { float2 v = ek2[i]; s_embk2[i] = packf2(v.x, v.y); }
        for (int i = t0; i < 24 * CELL; i += 512) s_fcW[i] = fc_W[i];
        if (t0 < 24) s_fcb[t0] = fc_b[t0];
        if (t0 < STEPS) s_net[t0] = net[t0];
        if (t0 < 64) { float2 v = ((const float2*)emb_start)[t0];
                       xh2[t0] = packf2(v.x, v.y); xh2[64 + t0] = 0u; }
    }
    float c = 0.0f;
    for (int t = 0; t < STEPS; ++t) {
        __syncthreads();
        floatx4 a0 = {0,0,0,0}, a1 = {0,0,0,0}, a2 = {0,0,0,0}, a3 = {0,0,0,0};
        const uint4* xp = (const uint4*)xh2;
#pragma unroll
        for (int kc = 0; kc < 8; ++kc) {
            half8_t af = __builtin_bit_cast(half8_t, xp[(kc << 2) + quad]);
            a0 = __builtin_amdgcn_mfma_f32_16x16x32_f16(af, bf0[kc], a0, 0, 0, 0);
            a1 = __builtin_amdgcn_mfma_f32_16x16x32_f16(af, bf1[kc], a1, 0, 0, 0);
            a2 = __builtin_amdgcn_mfma_f32_16x16x32_f16(af, bf2[kc], a2, 0, 0, 0);
            a3 = __builtin_amdgcn_mfma_f32_16x16x32_f16(af, bf3[kc], a3, 0, 0, 0);
        }
        if (lane < 16) {
            gates[rbase + lane]      = a0[0] + bias0;
            gates[rbase + 16 + lane] = a1[0] + bias1;
            gates[rbase + 32 + lane] = a2[0] + bias2;
            gates[rbase + 48 + lane] = a3[0] + bias3;
        }
        if (t >= 1 && wv < 6) {
            const int ti = t - 1;
            unsigned hu = xh2[64 + lane];
            const float* Wr = s_fcW + (((ti & 3) * 6) + wv) * CELL;
            typedef _Float16 h2t __attribute__((ext_vector_type(2)));
            h2t hh = __builtin_bit_cast(h2t, hu);
            float p2 = (float)hh[0] * Wr[2 * lane] + (float)hh[1] * Wr[2 * lane + 1];
#pragma unroll
            for (int off = 32; off >= 1; off >>= 1) p2 += __shfl_down(p2, off);
            if (lane == 0) logits[((ti & 1) << 3) + wv] = p2 + s_fcb[(ti & 3) * 6 + wv];
        }
        if (t >= 2 && t0 < 6) {
            const float* L = logits + ((t & 1) << 3);
            float l0 = L[0], l1 = L[1], l2 = L[2], l3 = L[3], l4 = L[4], l5 = L[5];
            float m = fmaxf(fmaxf(fmaxf(l0, l1), fmaxf(l2, l3)), fmaxf(l4, l5));
            float e0 = __expf(l0 - m), e1 = __expf(l1 - m), e2 = __expf(l2 - m);
            float e3 = __expf(l3 - m), e4 = __expf(l4 - m), e5 = __expf(l5 - m);
            float s = ((e0 + e1) + (e2 + e3)) + (e4 + e5);
            float mine = (t0 == 0) ? e0 : (t0 == 1) ? e1 : (t0 == 2) ? e2
                       : (t0 == 3) ? e3 : (t0 == 4) ? e4 : e5;
            out[(t - 2) * 6 + t0] = mine / s;
        }
        __syncthreads();
        if (t0 < CELL) {
            float ig = fast_sigmoid(gates[t0]);
            float fg = fast_sigmoid(gates[CELL + t0]);
            float gg = fast_tanh(gates[2 * CELL + t0]);
            float og = fast_sigmoid(gates[3 * CELL + t0]);
            c = fg * c + ig * gg;
            float h = og * fast_tanh(c);
            float hpv = __shfl_xor(h, 1);
            if ((t0 & 1) == 0) xh2[64 + (t0 >> 1)] = packf2(h, hpv);
        } else if (wv == 2 && t < STEPS - 1) {
            xh2[lane] = s_embk2[((((t + 1) & 3) * 6) + s_net[t + 1]) * 64 + lane];
        }
    }
    __syncthreads();
    if (wv < 6) {
        unsigned hu = xh2[64 + lane];
        const float* Wr = s_fcW + (((19 & 3) * 6) + wv) * CELL;
        typedef _Float16 h2t __attribute__((ext_vector_type(2)));
        h2t hh = __builtin_bit_cast(h2t, hu);
        float p2 = (float)hh[0] * Wr[2 * lane] + (float)hh[1] * Wr[2 * lane + 1];
#pragma unroll
        for (int off = 32; off >= 1; off >>= 1) p2 += __shfl_down(p2, off);
        if (lane == 0) logits[8 + wv] = p2 + s_fcb[(19 & 3) * 6 + wv];
    }
    if (t0 < 6) {
        const float* L = logits + 0;
        float l0 = L[0], l1 = L[1], l2 = L[2], l3 = L[3], l4 = L[4], l5 = L[5];
        float m = fmaxf(fmaxf(fmaxf(l0, l1), fmaxf(l2, l3)), fmaxf(l4, l5));
        float e0 = __expf(l0 - m), e1 = __expf(l1 - m), e2 = __expf(l2 - m);
        float e3 = __expf(l3 - m), e4 = __expf(l4 - m), e5 = __expf(l5 - m);
        float s = ((e0 + e1) + (e2 + e3)) + (e4 + e5);
        float mine = (t0 == 0) ? e0 : (t0 == 1) ? e1 : (t0 == 2) ? e2
                   : (t0 == 3) ? e3 : (t0 == 4) ? e4 : e5;
        out[18 * 6 + t0] = mine / s;
    }
    __syncthreads();
    if (t0 < 6) {
        const float* L = logits + 8;
        float l0 = L[0], l1 = L[1], l2 = L[2], l3 = L[3], l4 = L[4], l5 = L[5];
        float m = fmaxf(fmaxf(fmaxf(l0, l1), fmaxf(l2, l3)), fmaxf(l4, l5));
        float e0 = __expf(l0 - m), e1 = __expf(l1 - m), e2 = __expf(l2 - m);
        float e3 = __expf(l3 - m), e4 = __expf(l4 - m), e5 = __expf(l5 - m);
        float s = ((e0 + e1) + (e2 + e3)) + (e4 + e5);
        float mine = (t0 == 0) ? e0 : (t0 == 1) ? e1 : (t0 == 2) ? e2
                   : (t0 == 3) ? e3 : (t0 == 4) ? e4 : e5;
        out[19 * 6 + t0] = mine / s;
    }
}

extern "C" void kernel_launch(void* const* d_in, const int* in_sizes, int n_in,
                              void* d_out, int out_size, void* d_ws, size_t ws_size,
                              hipStream_t stream) {
    (void)in_sizes; (void)n_in; (void)out_size;
    const int*   net       = (const int*)d_in[0];
    // d_in[1] = reward, unused in forward
    const float* emb_start = (const float*)d_in[2];
    const float* emb_keys  = (const float*)d_in[3];
    const float* fc_W      = (const float*)d_in[4];
    const float* fc_b      = (const float*)d_in[5];
    const float* W_ih      = (const float*)d_in[6];
    const float* W_hh      = (const float*)d_in[7];
    const float* b_ih      = (const float*)d_in[8];
    const float* b_hh      = (const float*)d_in[9];
    float*       out       = (float*)d_out;

    if (ws_size >= (size_t)(262144 + 2048)) {
        uint4* wsf = (uint4*)d_ws;
        float* wsb = (float*)((char*)d_ws + 262144);
        hipLaunchKernelGGL(nas_conv_kernel, dim3(32), dim3(256), 0, stream,
                           W_ih, W_hh, b_ih, b_hh, wsf, wsb);
        hipLaunchKernelGGL(nas_policy_kernel, dim3(1), dim3(512), 0, stream,
                           net, emb_start, emb_keys, fc_W, fc_b, wsf, wsb, out);
    } else {
        hipLaunchKernelGGL(nas_policy_fb, dim3(1), dim3(512), 0, stream,
                           net, emb_start, emb_keys, fc_W, fc_b,
                           W_ih, W_hh, b_ih, b_hh, out);
    }
}